// Round 12
// baseline (114.180 us; speedup 1.0000x reference)
//
#include <hip/hip_runtime.h>
#include <hip/hip_bf16.h>

#define B_ 2
#define L_ 2048
#define H_ 8
#define D_ 64
#define SP_ 65       // STRIDE+1
#define NC_ 128      // level-1 chunks (16 rows each)
#define RS_ 512      // H_*D_ floats between consecutive seq rows

typedef __attribute__((ext_vector_type(8))) short bf16x8;
typedef __attribute__((ext_vector_type(16))) float f32x16;

static __device__ inline short f2bf(float x) {
    return __builtin_bit_cast(short, __float2bfloat16(x));
}

static __device__ inline bf16x8 ld8_bf16(const float* __restrict__ p) {
    float4 a = *(const float4*)p;
    float4 b = *(const float4*)(p + 4);
    bf16x8 r;
    r[0]=f2bf(a.x); r[1]=f2bf(a.y); r[2]=f2bf(a.z); r[3]=f2bf(a.w);
    r[4]=f2bf(b.x); r[5]=f2bf(b.y); r[6]=f2bf(b.z); r[7]=f2bf(b.w);
    return r;
}

static __device__ inline bf16x8 ones_frag() {
    bf16x8 r;
    short o = f2bf(1.f);
    #pragma unroll
    for (int t = 0; t < 8; ++t) r[t] = o;
    return r;
}

// ================= Kernel 1: strided partials + csum1 (input-only) ==========
// blk < 260 : strided residue units (4 waves/block, 1040 units) -> pB, zB
// blk < 772 : csum1 16-row V sums (4 waves/block, 2048 units)
__global__ __launch_bounds__(256) void stride_csum_k(const float* __restrict__ q,
                                                     const float* __restrict__ kk,
                                                     const float* __restrict__ v,
                                                     float* __restrict__ csum1,
                                                     float* __restrict__ pB,
                                                     float* __restrict__ zB) {
    __shared__ float LDS[4608];          // 4 waves x [32][36]
    int wib  = threadIdx.x >> 6;
    int lane = threadIdx.x & 63;
    int half = lane >> 5, ln = lane & 31;
    int blk  = blockIdx.x;

    if (blk < 260) {
        // ---- strided residue class mod 65: rows l = r + 65*s, s = 0..31
        int us = blk * 4 + wib;          // 0..1039
        int bh = us / SP_;
        int r  = us % SP_;
        int h = bh & 7, b = bh >> 3;
        const size_t base = (size_t)b * L_ * RS_ + (size_t)h * D_;
        float* Pw = LDS + wib * 1152;    // [32][36]

        bf16x8 bv0[2], bv1[2];
        #pragma unroll
        for (int kb = 0; kb < 2; ++kb) {
            int k0 = kb * 16 + half * 8;
            #pragma unroll
            for (int jj = 0; jj < 8; ++jj) {
                int lv = r + SP_ * (k0 + jj);
                lv = lv > L_ - 1 ? L_ - 1 : lv;
                const float* vr = v + base + (size_t)lv * RS_;
                bv0[kb][jj] = f2bf(vr[ln]);
                bv1[kb][jj] = f2bf(vr[32 + ln]);
            }
        }

        int lq = r + SP_ * ln;
        int lqc = lq > L_ - 1 ? L_ - 1 : lq;
        const float* qrow = q  + base + (size_t)lqc * RS_;
        const float* krow = kk + base + (size_t)lqc * RS_;
        f32x16 acc = {};
        #pragma unroll
        for (int kb = 0; kb < 4; ++kb) {
            bf16x8 a  = ld8_bf16(qrow + kb * 16 + half * 8);
            bf16x8 bb = ld8_bf16(krow + kb * 16 + half * 8);
            acc = __builtin_amdgcn_mfma_f32_32x32x16_bf16(a, bb, acc, 0, 0, 0);
        }
        #pragma unroll
        for (int rg = 0; rg < 16; ++rg) {
            int m = (rg & 3) + 8 * (rg >> 2) + 4 * half;
            bool act = (ln < m) && (r + SP_ * m < L_);
            Pw[m * 36 + ln] = act ? (__expf(0.125f * acc[rg]) - 1.f) : 0.f;
        }
        __syncthreads();

        f32x16 p0 = {}; f32x16 p1 = {}; f32x16 po = {};
        bf16x8 ones = ones_frag();
        #pragma unroll
        for (int kb = 0; kb < 2; ++kb) {
            int k0 = kb * 16 + half * 8;
            const float* pr = &Pw[ln * 36 + k0];
            float4 x = *(const float4*)pr;
            float4 y = *(const float4*)(pr + 4);
            bf16x8 ap;
            ap[0]=f2bf(x.x); ap[1]=f2bf(x.y); ap[2]=f2bf(x.z); ap[3]=f2bf(x.w);
            ap[4]=f2bf(y.x); ap[5]=f2bf(y.y); ap[6]=f2bf(y.z); ap[7]=f2bf(y.w);
            p0 = __builtin_amdgcn_mfma_f32_32x32x16_bf16(ap, bv0[kb], p0, 0, 0, 0);
            p1 = __builtin_amdgcn_mfma_f32_32x32x16_bf16(ap, bv1[kb], p1, 0, 0, 0);
            po = __builtin_amdgcn_mfma_f32_32x32x16_bf16(ap, ones,    po, 0, 0, 0);
        }
        float* pBr = pB + (size_t)bh * L_ * D_;
        float* zBr = zB + (size_t)bh * L_;
        #pragma unroll
        for (int rg = 0; rg < 16; ++rg) {
            int m = (rg & 3) + 8 * (rg >> 2) + 4 * half;
            int l = r + SP_ * m;
            if (l < L_) {
                pBr[(size_t)l * D_ + ln]      = p0[rg];
                pBr[(size_t)l * D_ + 32 + ln] = p1[rg];
                if (ln == 0) zBr[l] = po[rg];
            }
        }
    } else {
        // ---- csum1: 16-row chunk sums of V
        int uc = (blk - 260) * 4 + wib;  // 0..2047 = bh*128 + c
        int c = uc & (NC_ - 1);
        int bh = uc >> 7;
        int h = bh & 7, b = bh >> 3;
        const float* vb = v + (size_t)(b * L_ + c * 16) * RS_ + h * D_ + lane;
        float s = 0.f;
        #pragma unroll
        for (int l = 0; l < 16; ++l) s += vb[l * RS_];
        csum1[(size_t)uc * D_ + lane] = s;
    }
}

// ================= Kernel 2: local tiles + prefix + combine + out ===========
// 2-wave teams, 2 teams per 256-thr block (1024 tiles -> 512 blocks).
// Wave hf computes QK col-tile hf and PV output dims [32hf, 32hf+32);
// po (full-band row sums) from hf0, shared via LDS.
__global__ __launch_bounds__(256) void local_final_k(const float* __restrict__ q,
                                                     const float* __restrict__ kk,
                                                     const float* __restrict__ v,
                                                     const float* __restrict__ csum1,
                                                     const float* __restrict__ pB,
                                                     const float* __restrict__ zB,
                                                     float* __restrict__ out) {
    __shared__ float Pws[2][32 * 68];
    __shared__ float zs[2][32];
    int wib  = threadIdx.x >> 6;
    int lane = threadIdx.x & 63;
    int half = lane >> 5, ln = lane & 31;
    int tb = wib >> 1;                   // team in block
    int hf = wib & 1;                    // col-tile / dim-half
    int team = blockIdx.x * 2 + tb;      // 0..1023
    int bh = team >> 6;
    int T  = (team & 63) << 5;
    int h = bh & 7, b = bh >> 3;
    const size_t base = (size_t)b * L_ * RS_ + (size_t)h * D_;
    float* Pw = Pws[tb];
    int d0 = 32 * hf;

    // ---- V band prefetch (dims [d0,d0+32), rows T-16+[0,64))
    bf16x8 bv[4];
    #pragma unroll
    for (int kb = 0; kb < 4; ++kb) {
        #pragma unroll
        for (int jj = 0; jj < 8; ++jj) {
            int jr = T - 16 + kb * 16 + half * 8 + jj;
            jr = jr < 0 ? 0 : (jr > L_ - 1 ? L_ - 1 : jr);
            bv[kb][jj] = f2bf(v[base + (size_t)jr * RS_ + d0 + ln]);
        }
    }

    // ---- QK^T for this wave's 32-col tile
    const float* qrow = q + base + (size_t)(T + ln) * RS_;
    bf16x8 aq[4];
    #pragma unroll
    for (int kb = 0; kb < 4; ++kb) aq[kb] = ld8_bf16(qrow + kb * 16 + half * 8);

    int j = T - 16 + d0 + ln;
    j = j < 0 ? 0 : (j > L_ - 1 ? L_ - 1 : j);
    const float* krow = kk + base + (size_t)j * RS_;
    f32x16 acc = {};
    #pragma unroll
    for (int kb = 0; kb < 4; ++kb) {
        bf16x8 kf = ld8_bf16(krow + kb * 16 + half * 8);
        acc = __builtin_amdgcn_mfma_f32_32x32x16_bf16(aq[kb], kf, acc, 0, 0, 0);
    }

    // ---- weights (exp-1 masked + "+1" prefix-fold) into col half d0
    #pragma unroll
    for (int r = 0; r < 16; ++r) {
        int m = (r & 3) + 8 * (r >> 2) + 4 * half;
        float w;
        if (hf == 0) {
            bool act = (ln >= m) && (ln <= m + 16) && (T - 16 + ln >= 0);
            w = act ? (__expf(0.125f * acc[r]) - 1.f) : 0.f;
            if ((m < 16) && (ln >= 16) && (ln <= m + 16)) w += 1.f;
        } else {
            bool act = (ln <= m - 16);
            w = act ? (__expf(0.125f * acc[r]) - 1.f) : 0.f;
            if ((m >= 16) && (ln <= m - 16)) w += 1.f;
        }
        Pw[m * 68 + d0 + ln] = w;
    }
    __syncthreads();

    // ---- PV over full band for this wave's dims; po (full row sums) on hf0
    f32x16 p = {}; f32x16 po = {};
    bf16x8 ones = ones_frag();
    #pragma unroll
    for (int kb = 0; kb < 4; ++kb) {
        int k0 = kb * 16 + half * 8;
        const float* pr = &Pw[ln * 68 + k0];
        float4 x = *(const float4*)pr;
        float4 y = *(const float4*)(pr + 4);
        bf16x8 ap;
        ap[0]=f2bf(x.x); ap[1]=f2bf(x.y); ap[2]=f2bf(x.z); ap[3]=f2bf(x.w);
        ap[4]=f2bf(y.x); ap[5]=f2bf(y.y); ap[6]=f2bf(y.z); ap[7]=f2bf(y.w);
        p = __builtin_amdgcn_mfma_f32_32x32x16_bf16(ap, bv[kb], p, 0, 0, 0);
        if (hf == 0)
            po = __builtin_amdgcn_mfma_f32_32x32x16_bf16(ap, ones, po, 0, 0, 0);
    }
    if (hf == 0 && ln == 0) {
        #pragma unroll
        for (int r = 0; r < 16; ++r) {
            int m = (r & 3) + 8 * (r >> 2) + 4 * half;
            zs[tb][m] = po[r];
        }
    }

    // ---- prefix walk over csum1 (this wave's dims only), overlap with barrier
    int c1b = T >> 4;
    const float* cs1 = csum1 + (size_t)bh * NC_ * D_ + d0 + ln;
    float s0 = 0.f, s1 = 0.f, s2 = 0.f, s3 = 0.f;
    int cc = 0;
    for (; cc + 4 <= c1b; cc += 4) {
        s0 += cs1[(cc + 0) * D_]; s1 += cs1[(cc + 1) * D_];
        s2 += cs1[(cc + 2) * D_]; s3 += cs1[(cc + 3) * D_];
    }
    for (; cc < c1b; ++cc) s0 += cs1[cc * D_];
    float pr = (s0 + s1) + (s2 + s3);
    float ch = cs1[c1b * D_];
    __syncthreads();

    // ---- combine + divide + write out (this wave's 32 dims)
    const float* pBr = pB + (size_t)bh * L_ * D_;
    const float* zBr = zB + (size_t)bh * L_;
    #pragma unroll
    for (int r = 0; r < 16; ++r) {
        int m = (r & 3) + 8 * (r >> 2) + 4 * half;
        int i = T + m;
        float num = p[r] + pr + ((m & 16) ? ch : 0.f) + pBr[(size_t)i * D_ + d0 + ln];
        float zloc = zs[tb][m] - (float)((m & 15) + 1);
        float inv = 1.f / (zloc + zBr[i] + (float)(i + 1));
        out[base + (size_t)i * RS_ + d0 + ln] = num * inv;
    }
}

extern "C" void kernel_launch(void* const* d_in, const int* in_sizes, int n_in,
                              void* d_out, int out_size, void* d_ws, size_t ws_size,
                              hipStream_t stream) {
    const float* q = (const float*)d_in[0];
    const float* k = (const float*)d_in[1];
    const float* v = (const float*)d_in[2];
    // d_in[3] = attn_mask: deterministic causal — not read.
    float* out = (float*)d_out;

    float* csum1 = (float*)d_ws;                          // 131072 f
    float* pB    = csum1 + (size_t)B_ * H_ * NC_ * D_;    // 2097152 f
    float* zB    = pB    + (size_t)B_ * H_ * L_ * D_;     // 32768 f

    // 260 strided + 512 csum1 blocks (all input-only)
    stride_csum_k<<<772, 256, 0, stream>>>(q, k, v, csum1, pB, zB);
    // local tiles + prefix + combine: 1024 teams, 2 per block
    local_final_k<<<512, 256, 0, stream>>>(q, k, v, csum1, pB, zB, out);
}

// Round 13
// 111.499 us; speedup vs baseline: 1.0240x; 1.0240x over previous
//
#include <hip/hip_runtime.h>
#include <hip/hip_bf16.h>

#define B_ 2
#define L_ 2048
#define H_ 8
#define D_ 64
#define SP_ 65       // STRIDE+1
#define NC_ 128      // level-1 chunks (16 rows each)
#define RS_ 512      // H_*D_ floats between consecutive seq rows

typedef __attribute__((ext_vector_type(8))) short bf16x8;
typedef __attribute__((ext_vector_type(16))) float f32x16;

static __device__ inline short f2bf(float x) {
    return __builtin_bit_cast(short, __float2bfloat16(x));
}

static __device__ inline bf16x8 ld8_bf16(const float* __restrict__ p) {
    float4 a = *(const float4*)p;
    float4 b = *(const float4*)(p + 4);
    bf16x8 r;
    r[0]=f2bf(a.x); r[1]=f2bf(a.y); r[2]=f2bf(a.z); r[3]=f2bf(a.w);
    r[4]=f2bf(b.x); r[5]=f2bf(b.y); r[6]=f2bf(b.z); r[7]=f2bf(b.w);
    return r;
}

static __device__ inline bf16x8 ones_frag() {
    bf16x8 r;
    short o = f2bf(1.f);
    #pragma unroll
    for (int t = 0; t < 8; ++t) r[t] = o;
    return r;
}

// ================= Kernel 1: ALL input-only partials, one launch ============
// blk <  512 : local 32-row tiles, 2-wave teams (2 teams/block; 1024 tiles)
// blk <  772 : strided residue units (4 waves/block, 1040 units)
// blk < 1284 : csum1 16-row V sums (4 waves/block, 2048 units)
__global__ __launch_bounds__(256) void partials_k(const float* __restrict__ q,
                                                  const float* __restrict__ kk,
                                                  const float* __restrict__ v,
                                                  float* __restrict__ csum1,
                                                  float* __restrict__ pA,
                                                  float* __restrict__ zA,
                                                  float* __restrict__ pB,
                                                  float* __restrict__ zB) {
    __shared__ float LDS[4608];          // local: 2 teams x 32x68; strided: 4 x 32x36
    int wib  = threadIdx.x >> 6;
    int lane = threadIdx.x & 63;
    int half = lane >> 5, ln = lane & 31;
    int blk  = blockIdx.x;

    if (blk < 512) {
        // ---------- local tile, 2-wave team: wave hf = col-tile hf, dims [32hf,32hf+32)
        int tb = wib >> 1;
        int hf = wib & 1;
        int team = blk * 2 + tb;         // 0..1023
        int bh = team >> 6;
        int T  = (team & 63) << 5;
        int h = bh & 7, b = bh >> 3;
        const size_t base = (size_t)b * L_ * RS_ + (size_t)h * D_;
        float* Pw = LDS + tb * 2176;     // [32][68]
        int d0 = 32 * hf;

        // V prefetch: band rows, this wave's dims [d0, d0+32)
        bf16x8 bv[4];
        #pragma unroll
        for (int kb = 0; kb < 4; ++kb) {
            #pragma unroll
            for (int jj = 0; jj < 8; ++jj) {
                int jr = T - 16 + kb * 16 + half * 8 + jj;
                jr = jr < 0 ? 0 : (jr > L_ - 1 ? L_ - 1 : jr);
                bv[kb][jj] = f2bf(v[base + (size_t)jr * RS_ + d0 + ln]);
            }
        }

        // QK^T for this wave's 32-col tile
        const float* qrow = q + base + (size_t)(T + ln) * RS_;
        bf16x8 aq[4];
        #pragma unroll
        for (int kb = 0; kb < 4; ++kb) aq[kb] = ld8_bf16(qrow + kb * 16 + half * 8);

        int j = T - 16 + d0 + ln;
        j = j < 0 ? 0 : (j > L_ - 1 ? L_ - 1 : j);
        const float* krow = kk + base + (size_t)j * RS_;
        f32x16 acc = {};
        #pragma unroll
        for (int kb = 0; kb < 4; ++kb) {
            bf16x8 kf = ld8_bf16(krow + kb * 16 + half * 8);
            acc = __builtin_amdgcn_mfma_f32_32x32x16_bf16(aq[kb], kf, acc, 0, 0, 0);
        }

        // weights (exp-1 masked + "+1" prefix fold) into this wave's col half
        #pragma unroll
        for (int r = 0; r < 16; ++r) {
            int m = (r & 3) + 8 * (r >> 2) + 4 * half;
            float w;
            if (hf == 0) {
                bool act = (ln >= m) && (ln <= m + 16) && (T - 16 + ln >= 0);
                w = act ? (__expf(0.125f * acc[r]) - 1.f) : 0.f;
                if ((m < 16) && (ln >= 16) && (ln <= m + 16)) w += 1.f;
            } else {
                bool act = (ln <= m - 16);
                w = act ? (__expf(0.125f * acc[r]) - 1.f) : 0.f;
                if ((m >= 16) && (ln <= m - 16)) w += 1.f;
            }
            Pw[m * 68 + d0 + ln] = w;
        }
        __syncthreads();

        // PV over full 64-col band, this wave's 32 output dims (+ po on hf==1)
        f32x16 p = {}; f32x16 po = {};
        bf16x8 ones = ones_frag();
        #pragma unroll
        for (int kb = 0; kb < 4; ++kb) {
            int k0 = kb * 16 + half * 8;
            const float* pr = &Pw[ln * 68 + k0];
            float4 x = *(const float4*)pr;
            float4 y = *(const float4*)(pr + 4);
            bf16x8 ap;
            ap[0]=f2bf(x.x); ap[1]=f2bf(x.y); ap[2]=f2bf(x.z); ap[3]=f2bf(x.w);
            ap[4]=f2bf(y.x); ap[5]=f2bf(y.y); ap[6]=f2bf(y.z); ap[7]=f2bf(y.w);
            p = __builtin_amdgcn_mfma_f32_32x32x16_bf16(ap, bv[kb], p, 0, 0, 0);
            if (hf == 1)
                po = __builtin_amdgcn_mfma_f32_32x32x16_bf16(ap, ones, po, 0, 0, 0);
        }

        float* pAr = pA + (size_t)bh * L_ * D_;
        float* zAr = zA + (size_t)bh * L_;
        #pragma unroll
        for (int r = 0; r < 16; ++r) {
            int m = (r & 3) + 8 * (r >> 2) + 4 * half;
            int i = T + m;
            pAr[(size_t)i * D_ + d0 + ln] = p[r];
            if (hf == 1 && ln == 0)
                zAr[i] = po[r] - (float)((m & 15) + 1);
        }
    } else if (blk < 772) {
        // ---------- strided residue class mod 65: rows l = r + 65*s, s=0..31
        int us = (blk - 512) * 4 + wib;  // 0..1039
        int bh = us / SP_;
        int r  = us % SP_;
        int h = bh & 7, b = bh >> 3;
        const size_t base = (size_t)b * L_ * RS_ + (size_t)h * D_;
        float* Pw = LDS + wib * 1152;    // [32][36]

        bf16x8 bv0[2], bv1[2];
        #pragma unroll
        for (int kb = 0; kb < 2; ++kb) {
            int k0 = kb * 16 + half * 8;
            #pragma unroll
            for (int jj = 0; jj < 8; ++jj) {
                int lv = r + SP_ * (k0 + jj);
                lv = lv > L_ - 1 ? L_ - 1 : lv;
                const float* vr = v + base + (size_t)lv * RS_;
                bv0[kb][jj] = f2bf(vr[ln]);
                bv1[kb][jj] = f2bf(vr[32 + ln]);
            }
        }

        int lq = r + SP_ * ln;
        int lqc = lq > L_ - 1 ? L_ - 1 : lq;
        const float* qrow = q  + base + (size_t)lqc * RS_;
        const float* krow = kk + base + (size_t)lqc * RS_;
        f32x16 acc = {};
        #pragma unroll
        for (int kb = 0; kb < 4; ++kb) {
            bf16x8 a  = ld8_bf16(qrow + kb * 16 + half * 8);
            bf16x8 bb = ld8_bf16(krow + kb * 16 + half * 8);
            acc = __builtin_amdgcn_mfma_f32_32x32x16_bf16(a, bb, acc, 0, 0, 0);
        }
        #pragma unroll
        for (int rg = 0; rg < 16; ++rg) {
            int m = (rg & 3) + 8 * (rg >> 2) + 4 * half;
            bool act = (ln < m) && (r + SP_ * m < L_);
            Pw[m * 36 + ln] = act ? (__expf(0.125f * acc[rg]) - 1.f) : 0.f;
        }
        __syncthreads();

        f32x16 p0 = {}; f32x16 p1 = {}; f32x16 po = {};
        bf16x8 ones = ones_frag();
        #pragma unroll
        for (int kb = 0; kb < 2; ++kb) {
            int k0 = kb * 16 + half * 8;
            const float* pr = &Pw[ln * 36 + k0];
            float4 x = *(const float4*)pr;
            float4 y = *(const float4*)(pr + 4);
            bf16x8 ap;
            ap[0]=f2bf(x.x); ap[1]=f2bf(x.y); ap[2]=f2bf(x.z); ap[3]=f2bf(x.w);
            ap[4]=f2bf(y.x); ap[5]=f2bf(y.y); ap[6]=f2bf(y.z); ap[7]=f2bf(y.w);
            p0 = __builtin_amdgcn_mfma_f32_32x32x16_bf16(ap, bv0[kb], p0, 0, 0, 0);
            p1 = __builtin_amdgcn_mfma_f32_32x32x16_bf16(ap, bv1[kb], p1, 0, 0, 0);
            po = __builtin_amdgcn_mfma_f32_32x32x16_bf16(ap, ones,    po, 0, 0, 0);
        }
        float* pBr = pB + (size_t)bh * L_ * D_;
        float* zBr = zB + (size_t)bh * L_;
        #pragma unroll
        for (int rg = 0; rg < 16; ++rg) {
            int m = (rg & 3) + 8 * (rg >> 2) + 4 * half;
            int l = r + SP_ * m;
            if (l < L_) {
                pBr[(size_t)l * D_ + ln]      = p0[rg];
                pBr[(size_t)l * D_ + 32 + ln] = p1[rg];
                if (ln == 0) zBr[l] = po[rg];
            }
        }
    } else {
        // ---------- csum1: 16-row chunk sums of V
        int uc = (blk - 772) * 4 + wib;  // 0..2047 = bh*128 + c
        int c = uc & (NC_ - 1);
        int bh = uc >> 7;
        int h = bh & 7, b = bh >> 3;
        const float* vb = v + (size_t)(b * L_ + c * 16) * RS_ + h * D_ + lane;
        float s = 0.f;
        #pragma unroll
        for (int l = 0; l < 16; ++l) s += vb[l * RS_];
        csum1[(size_t)uc * D_ + lane] = s;
    }
}

// ================= Kernel 2: combine + prefix + divide (streaming) ==========
// One wave per 8-row group (4096 waves, 1024 blocks). Lane = dim.
__global__ __launch_bounds__(256) void combine_k(const float* __restrict__ csum1,
                                                 const float* __restrict__ pA,
                                                 const float* __restrict__ zA,
                                                 const float* __restrict__ pB,
                                                 const float* __restrict__ zB,
                                                 float* __restrict__ out) {
    int wib  = threadIdx.x >> 6;
    int lane = threadIdx.x & 63;
    int u = blockIdx.x * 4 + wib;        // 0..4095
    int bh = u >> 8;
    int g  = u & 255;                    // 8-row group
    int i0 = g << 3;
    int c1 = i0 >> 4;                    // full 16-row chunks below this group
    int h = bh & 7, b = bh >> 3;

    const float* zAr = zA + (size_t)bh * L_;
    const float* zBr = zB + (size_t)bh * L_;
    // z prefetch first (starts the reciprocal chain early)
    float zsum[8];
    #pragma unroll
    for (int r = 0; r < 8; ++r) {
        int i = i0 + r;
        zsum[r] = zAr[i] + zBr[i] + (float)(i + 1);
    }

    // prefix walk over csum1 (L2-hot, independent loads, 4-way unrolled)
    const float* cs1 = csum1 + (size_t)bh * NC_ * D_ + lane;
    float s0 = 0.f, s1 = 0.f, s2 = 0.f, s3 = 0.f;
    int cc = 0;
    for (; cc + 4 <= c1; cc += 4) {
        s0 += cs1[(cc + 0) * D_]; s1 += cs1[(cc + 1) * D_];
        s2 += cs1[(cc + 2) * D_]; s3 += cs1[(cc + 3) * D_];
    }
    for (; cc < c1; ++cc) s0 += cs1[cc * D_];
    float pr = (s0 + s1) + (s2 + s3);

    const float* pAr = pA + (size_t)bh * L_ * D_;
    const float* pBr = pB + (size_t)bh * L_ * D_;
    const size_t obase = (size_t)b * L_ * RS_ + (size_t)h * D_;

    #pragma unroll
    for (int r = 0; r < 8; ++r) {
        int i = i0 + r;
        float num = pAr[(size_t)i * D_ + lane] + pBr[(size_t)i * D_ + lane] + pr;
        out[obase + (size_t)i * RS_ + lane] = num / zsum[r];
    }
}

extern "C" void kernel_launch(void* const* d_in, const int* in_sizes, int n_in,
                              void* d_out, int out_size, void* d_ws, size_t ws_size,
                              hipStream_t stream) {
    const float* q = (const float*)d_in[0];
    const float* k = (const float*)d_in[1];
    const float* v = (const float*)d_in[2];
    // d_in[3] = attn_mask: deterministic causal — not read.
    float* out = (float*)d_out;

    float* csum1 = (float*)d_ws;                          // 131072 f
    float* pA    = csum1 + (size_t)B_ * H_ * NC_ * D_;    // 2097152 f
    float* zA    = pA    + (size_t)B_ * H_ * L_ * D_;     // 32768 f
    float* pB    = zA    + (size_t)B_ * H_ * L_;          // 2097152 f
    float* zB    = pB    + (size_t)B_ * H_ * L_ * D_;     // 32768 f

    // 512 local-team + 260 strided + 512 csum1 blocks
    partials_k<<<1284, 256, 0, stream>>>(q, k, v, csum1, pA, zA, pB, zB);
    // combine: 4096 8-row groups, 4 waves/block
    combine_k<<<1024, 256, 0, stream>>>(csum1, pA, zA, pB, zB, out);
}